// Round 22
// baseline (255.018 us; speedup 1.0000x reference)
//
#include <hip/hip_runtime.h>

typedef unsigned int u32;
typedef unsigned short u16;
typedef unsigned char u8;
typedef _Float16 half8 __attribute__((ext_vector_type(8)));
typedef float f32x4 __attribute__((ext_vector_type(4)));
typedef float f32x2 __attribute__((ext_vector_type(2)));

#define STRIDE 16384   // fixed edge capacity per 256-node bucket (mean 8192, ~90 sigma)

// ---------------- fused partition + conversions ----------------
// Blocks [0,nba): partition edges into fixed-stride bucket regions (cnt pre-zeroed).
// Blocks [nba,nba+nbx): x -> f16 (GEMM) + fp8 quarter-major table xq4[q][node][8 u32].
// Rest: W -> f16.
__global__ __launch_bounds__(256) void part_k(const int* __restrict__ src, const int* __restrict__ dst,
                                              int E, u32* __restrict__ cnt,
                                              u32* __restrict__ packed, int nbkt,
                                              const float* __restrict__ x, u16* __restrict__ xh,
                                              u32* __restrict__ xq,
                                              const float* __restrict__ W, u16* __restrict__ wh,
                                              int N, int nba, int nbx) {
  int b = blockIdx.x, tid = threadIdx.x;
  if (b < nba) {                              // ---- partition ----
    __shared__ u32 h[512];
    for (int t = tid; t < 512; t += 256) h[t] = 0u;
    __syncthreads();
    int base = b * 8192;
    for (int it = 0; it < 32; it++) {
      int i = base + it * 256 + tid;
      if (i < E) atomicAdd(&h[(u32)dst[i] >> 8], 1u);
    }
    __syncthreads();
    for (int t = tid; t < nbkt; t += 256) {
      u32 c = h[t];
      h[t] = c ? atomicAdd(&cnt[t], c) : 0u;  // reserve range within fixed region
    }
    __syncthreads();
    for (int it = 0; it < 32; it++) {
      int i = base + it * 256 + tid;
      if (i < E) {
        u32 d = (u32)dst[i];
        u32 pos = atomicAdd(&h[d >> 8], 1u);  // LDS atomic (u32 fast path)
        if (pos < (u32)STRIDE)                // statistically unreachable guard
          packed[(size_t)(d >> 8) * STRIDE + pos] = (u32)src[i] | ((d & 255u) << 24);
      }
    }
  } else if (b < nba + nbx) {                 // ---- x -> f16 + quarter-major fp8 ----
    int i = (b - nba) * 256 + tid;            // i-th float4: row = i>>5, c = i&31
    if (i < N * 32) {
      const float4 v = *(const float4*)(x + (size_t)i * 4);
      u32 p0 = __builtin_bit_cast(u32, __builtin_amdgcn_cvt_pkrtz(v.x, v.y));
      u32 p1 = __builtin_bit_cast(u32, __builtin_amdgcn_cvt_pkrtz(v.z, v.w));
      *(uint2*)(xh + (size_t)i * 4) = uint2{p0, p1};
      u32 q = 0;
      q = __builtin_amdgcn_cvt_pk_fp8_f32(v.x, v.y, q, false);
      q = __builtin_amdgcn_cvt_pk_fp8_f32(v.z, v.w, q, true);
      int row = i >> 5, c = i & 31;
      int qt = c >> 3, w = c & 7;             // quarter, word-in-quarter
      xq[(size_t)qt * (N * 8) + (size_t)row * 8 + w] = q;
    }
  } else {                                    // ---- W -> f16 ----
    int i = (b - nba - nbx) * 256 + tid;
    if (i < 8192) {
      const float4 v = *(const float4*)(W + (size_t)i * 4);
      u32 p0 = __builtin_bit_cast(u32, __builtin_amdgcn_cvt_pkrtz(v.x, v.y));
      u32 p1 = __builtin_bit_cast(u32, __builtin_amdgcn_cvt_pkrtz(v.z, v.w));
      *(uint2*)(wh + (size_t)i * 4) = uint2{p0, p1};
    }
  }
}

// ---------------- per-bucket counting sort -> offsets[nbkt][257] + fixed-stride ssrc + nodeperm ----------------
__global__ __launch_bounds__(256) void bucket_k(const u32* __restrict__ packed,
                                                const u32* __restrict__ cnt, int N,
                                                u32* __restrict__ offsets, int* __restrict__ ssrc,
                                                u8* __restrict__ nodeperm) {
  __shared__ u32 c256[256];
  __shared__ u32 scn[256];
  __shared__ u32 cur[256];
  int b = blockIdx.x, t = threadIdx.x;
  size_t fb = (size_t)b * STRIDE;             // fixed region base
  u32 cb = cnt[b]; if (cb > (u32)STRIDE) cb = (u32)STRIDE;
  c256[t] = 0u;
  __syncthreads();
  for (u32 j = t; j < cb; j += 256) atomicAdd(&c256[packed[fb + j] >> 24], 1u);
  __syncthreads();
  u32 v = c256[t];
  scn[t] = v;
  __syncthreads();
  for (int off = 1; off < 256; off <<= 1) {
    u32 x = (t >= off) ? scn[t - off] : 0u;
    __syncthreads();
    scn[t] += x;
    __syncthreads();
  }
  u32 lbase = scn[t] - v;                     // local exclusive base of this node's segment
  int node = b * 256 + t;
  int lastT = N - 1 - b * 256; if (lastT > 255) lastT = 255;
  u32* orow = offsets + (size_t)b * 257;      // per-bucket row: no cross-bucket aliasing
  if (node < N) {
    orow[t] = (u32)(fb + lbase);
    if (t == lastT) orow[t + 1] = (u32)(fb + lbase + v);   // bucket-private terminal
  }
  cur[t] = lbase;
  __syncthreads();
  for (u32 j = t; j < cb; j += 256) {
    u32 w = packed[fb + j];
    u32 pos = atomicAdd(&cur[w >> 24], 1u);   // LDS atomic (u32)
    ssrc[fb + pos] = (int)(w & 0xFFFFFFu);
  }
  // degree-rank permutation per 32-node group (ascending degree, stable)
  {
    int g = t >> 5, l = t & 31;
    u32 mykey = c256[t] * 256u + (u32)l;
    const u32* cg = &c256[g * 32];
    u32 rank = 0;
#pragma unroll 8
    for (int l2 = 0; l2 < 32; l2++) {
      u32 k2 = cg[l2] * 256u + (u32)l2;
      rank += (k2 < mykey) ? 1u : 0u;
    }
    nodeperm[(size_t)b * 256 + g * 32 + rank] = (u8)l;
  }
}

// ---------------- fused aggregate + GEMM, 4 waves / 32 nodes per block ----------------
// Phase 1: 4 feature-quarter passes; during pass q all blocks gather from the 3.2MB slice
// xq4[q] (fits one XCD L2). 8-lane subgroups (lane = 4 feats, dword loads); 8 nodes per
// wave concurrent (adjacent degree ranks); R12 quad loop + idx prefetch; no barriers
// between passes. Phase 2: 2 strips x 2 ct-halves; f16 MFMA (unchanged).
#define DEC1(vv, P0, P1) { f32x2 p;                                      \
    p = __builtin_amdgcn_cvt_pk_f32_fp8((vv), false); P0 += p;           \
    p = __builtin_amdgcn_cvt_pk_f32_fp8((vv), true);  P1 += p; }

__global__ __launch_bounds__(256) void fuse_k(const int* __restrict__ ssrc,
                                              const u32* __restrict__ offsets,
                                              const u32* __restrict__ xq,
                                              const u16* __restrict__ xh,
                                              const u16* __restrict__ wh,
                                              const float* __restrict__ bias,
                                              const u8* __restrict__ nodeperm,
                                              float* __restrict__ out, int N) {
  __shared__ u16 mlds[32][136];               // means (f16), padded stride
  int wv = threadIdx.x >> 6, lane = threadIdx.x & 63;
  int sg = lane >> 3, c8 = lane & 7;          // 8 subgroups x 8 lanes
  int nbase = blockIdx.x * 32;

  int ln = nodeperm[(size_t)nbase + wv * 8 + sg];   // adjacent ranks within wave
  int node = nbase + ln;
  u32 s0 = 0, s1 = 0;
  if (node < N) {
    size_t oi = (size_t)(node >> 8) * 257 + (node & 255);
    s0 = offsets[oi]; s1 = offsets[oi + 1];
  }
  u32 deg = s1 - s0;
  float inv = 1.0f / (float)(deg ? deg : 1u);

#pragma unroll 1
  for (int p = 0; p < 4; p++) {
    const u32* xqp = xq + (size_t)p * ((size_t)N * 8);
    f32x2 P0{0.f, 0.f}, P1{0.f, 0.f};
    if (node < N) {
      u32 j = s0;
      u32 nq = deg >> 2;
      if (nq) {
        uint4 iA = *(const uint4*)(ssrc + j);
        for (u32 q = 1; q < nq; q++) {
          uint4 iN = *(const uint4*)(ssrc + j + 4);   // prefetch next quad's indices
          u32 v0 = xqp[((size_t)iA.x << 3) + c8];
          u32 v1 = xqp[((size_t)iA.y << 3) + c8];
          u32 v2 = xqp[((size_t)iA.z << 3) + c8];
          u32 v3 = xqp[((size_t)iA.w << 3) + c8];
          DEC1(v0, P0, P1) DEC1(v1, P0, P1) DEC1(v2, P0, P1) DEC1(v3, P0, P1)
          iA = iN; j += 4;
        }
        {
          u32 v0 = xqp[((size_t)iA.x << 3) + c8];
          u32 v1 = xqp[((size_t)iA.y << 3) + c8];
          u32 v2 = xqp[((size_t)iA.z << 3) + c8];
          u32 v3 = xqp[((size_t)iA.w << 3) + c8];
          DEC1(v0, P0, P1) DEC1(v1, P0, P1) DEC1(v2, P0, P1) DEC1(v3, P0, P1)
          j += 4;
        }
      }
      for (; j < s1; j++) {
        u32 v = xqp[((size_t)(u32)ssrc[j] << 3) + c8];
        DEC1(v, P0, P1)
      }
    }
    // write this node's feature-quarter mean (feats p*32 + c8*4 .. +3)
    u32 o0 = __builtin_bit_cast(u32, __builtin_amdgcn_cvt_pkrtz(P0.x * inv, P0.y * inv));
    u32 o1 = __builtin_bit_cast(u32, __builtin_amdgcn_cvt_pkrtz(P1.x * inv, P1.y * inv));
    *(uint2*)&mlds[ln][p * 32 + c8 * 4] = uint2{o0, o1};
  }
  __syncthreads();

  // ---- phase 2: 2 strips x 2 col-halves; wave = (strip, half); f16 MFMA ----
  int la = lane & 15, lb = lane >> 4;
  int strip = wv & 1, ch = wv >> 1;
  int rbase = nbase + strip * 16;
  half8 a[8];
  const u16* ab = xh + ((size_t)(rbase + la) << 7) + lb * 8;
#pragma unroll
  for (int kb = 0; kb < 4; kb++) a[kb] = *(const half8*)(ab + kb * 32);
#pragma unroll
  for (int kb = 0; kb < 4; kb++)
    a[4 + kb] = *(const half8*)(&mlds[strip * 16 + la][kb * 32 + lb * 8]);

#pragma unroll
  for (int c = 0; c < 4; c++) {
    int ct = ch * 4 + c;
    f32x4 acc = { 0.f, 0.f, 0.f, 0.f };
    const u16* bbase = wh + ((size_t)(ct * 16 + la) << 8) + lb * 8;
#pragma unroll
    for (int kb = 0; kb < 8; kb++) {
      half8 b = *(const half8*)(bbase + kb * 32);
      acc = __builtin_amdgcn_mfma_f32_16x16x32_f16(a[kb], b, acc, 0, 0, 0);
    }
    float bc = bias[ct * 16 + la];
#pragma unroll
    for (int jj = 0; jj < 4; jj++) {
      int rr = rbase + lb * 4 + jj;
      if (rr < N) out[((size_t)rr << 7) + ct * 16 + la] = acc[jj] + bc;
    }
  }
}

extern "C" void kernel_launch(void* const* d_in, const int* in_sizes, int n_in,
                              void* d_out, int out_size, void* d_ws, size_t ws_size,
                              hipStream_t stream) {
  const float* x    = (const float*)d_in[0];
  const int*   ei   = (const int*)d_in[1];
  const float* W    = (const float*)d_in[2];
  const float* bias = (const float*)d_in[3];
  const int N = in_sizes[0] / 128;
  const int E = in_sizes[1] / 2;
  const int nbkt = (N + 255) >> 8;           // 256-node buckets (391)
  const int* src = ei;
  const int* dst = ei + E;
  float* out = (float*)d_out;

  // packed fixed-stride regions live in d_out (25.6 MB < 51.2; dead before fuse_k writes out)
  u32* packed = (u32*)d_out;                 // nbkt * STRIDE

  char* ws = (char*)d_ws;
  int* ssrc = (int*)ws;                      // nbkt * STRIDE (fixed-stride sorted srcs)
  size_t off = ((size_t)nbkt * STRIDE * 4 + 255) & ~(size_t)255;
  u32* cnt = (u32*)(ws + off);               // nbkt
  u32* offsets = cnt + nbkt;                 // nbkt * 257
  off += ((size_t)(nbkt + nbkt * 257) * 4 + 255) & ~(size_t)255;
  off = (off + 255) & ~(size_t)255;
  u16* xh = (u16*)(ws + off);                // N*128 f16 (GEMM A-half)
  off += (size_t)N * 128 * 2;
  off = (off + 255) & ~(size_t)255;
  u32* xq = (u32*)(ws + off);                // 4 x N*8 u32 (quarter-major fp8 table)
  off += (size_t)N * 128;
  off = (off + 255) & ~(size_t)255;
  u16* wh = (u16*)(ws + off);                // 128*256 f16
  off += (size_t)128 * 256 * 2;
  off = (off + 255) & ~(size_t)255;
  u8* nodeperm = (u8*)(ws + off);            // nbkt*256 bytes

  const int nbx = (N * 32 + 255) / 256;
  const int nba = (E + 8191) / 8192;
  hipMemsetAsync(cnt, 0, (size_t)nbkt * 4, stream);
  part_k<<<nba + nbx + 32, 256, 0, stream>>>(src, dst, E, cnt, packed, nbkt,
                                             x, xh, xq, W, wh, N, nba, nbx);
  bucket_k<<<nbkt, 256, 0, stream>>>(packed, cnt, N, offsets, ssrc, nodeperm);
  fuse_k<<<(N + 31) / 32, 256, 0, stream>>>(ssrc, offsets, xq, xh, wh, bias, nodeperm, out, N);
}

// Round 23
// 178.935 us; speedup vs baseline: 1.4252x; 1.4252x over previous
//
#include <hip/hip_runtime.h>

typedef unsigned int u32;
typedef unsigned short u16;
typedef unsigned char u8;
typedef _Float16 half8 __attribute__((ext_vector_type(8)));
typedef float f32x4 __attribute__((ext_vector_type(4)));
typedef float f32x2 __attribute__((ext_vector_type(2)));

#define STRIDE 16384   // fixed edge capacity per 256-node bucket (mean 8192, ~90 sigma)

// ---------------- fused partition + conversions ----------------
// Blocks [0,nba): partition edges into fixed-stride bucket regions (cnt pre-zeroed);
//   dst staged in LDS (one global read instead of two), int4-vectorized.
// Blocks [nba,nba+nbx): x -> f16 (GEMM) + fp8 (gather). Rest: W -> f16.
__global__ __launch_bounds__(256) void part_k(const int* __restrict__ src, const int* __restrict__ dst,
                                              int E, u32* __restrict__ cnt,
                                              u32* __restrict__ packed, int nbkt,
                                              const float* __restrict__ x, u16* __restrict__ xh,
                                              u32* __restrict__ xq,
                                              const float* __restrict__ W, u16* __restrict__ wh,
                                              int N, int nba, int nbx) {
  __shared__ u32 h[512];
  __shared__ int dstS[8192];                  // 32 KB staged dst
  int b = blockIdx.x, tid = threadIdx.x;
  if (b < nba) {                              // ---- partition ----
    for (int t = tid; t < 512; t += 256) h[t] = 0u;
    __syncthreads();
    int base = b * 8192;
    int nE = E - base; if (nE > 8192) nE = 8192;
    for (int it = 0; it < 8; it++) {
      int li = it * 1024 + tid * 4;
      int i = base + li;
      if (li + 3 < nE) {
        int4 d4 = *(const int4*)(dst + i);
        *(int4*)&dstS[li] = d4;               // b128 LDS write, conflict-free
        atomicAdd(&h[(u32)d4.x >> 8], 1u);
        atomicAdd(&h[(u32)d4.y >> 8], 1u);
        atomicAdd(&h[(u32)d4.z >> 8], 1u);
        atomicAdd(&h[(u32)d4.w >> 8], 1u);
      } else {
        for (int k = 0; k < 4; k++) {
          if (li + k < nE) {
            int d = dst[i + k];
            dstS[li + k] = d;
            atomicAdd(&h[(u32)d >> 8], 1u);
          }
        }
      }
    }
    __syncthreads();
    for (int t = tid; t < nbkt; t += 256) {
      u32 c = h[t];
      h[t] = c ? atomicAdd(&cnt[t], c) : 0u;  // reserve range within fixed region
    }
    __syncthreads();
    for (int it = 0; it < 8; it++) {
      int li = it * 1024 + tid * 4;
      int i = base + li;
      if (li + 3 < nE) {
        int4 s4 = *(const int4*)(src + i);
        u32 d0 = (u32)dstS[li],     d1 = (u32)dstS[li + 1];
        u32 d2 = (u32)dstS[li + 2], d3 = (u32)dstS[li + 3];
        u32 p0 = atomicAdd(&h[d0 >> 8], 1u);
        u32 p1 = atomicAdd(&h[d1 >> 8], 1u);
        u32 p2 = atomicAdd(&h[d2 >> 8], 1u);
        u32 p3 = atomicAdd(&h[d3 >> 8], 1u);
        if (p0 < (u32)STRIDE) packed[(size_t)(d0 >> 8) * STRIDE + p0] = (u32)s4.x | ((d0 & 255u) << 24);
        if (p1 < (u32)STRIDE) packed[(size_t)(d1 >> 8) * STRIDE + p1] = (u32)s4.y | ((d1 & 255u) << 24);
        if (p2 < (u32)STRIDE) packed[(size_t)(d2 >> 8) * STRIDE + p2] = (u32)s4.z | ((d2 & 255u) << 24);
        if (p3 < (u32)STRIDE) packed[(size_t)(d3 >> 8) * STRIDE + p3] = (u32)s4.w | ((d3 & 255u) << 24);
      } else {
        for (int k = 0; k < 4; k++) {
          if (li + k < nE) {
            u32 d = (u32)dstS[li + k];
            u32 pos = atomicAdd(&h[d >> 8], 1u);
            if (pos < (u32)STRIDE)
              packed[(size_t)(d >> 8) * STRIDE + pos] = (u32)src[i + k] | ((d & 255u) << 24);
          }
        }
      }
    }
  } else if (b < nba + nbx) {                 // ---- x -> f16 + fp8 ----
    int i = (b - nba) * 256 + tid;            // i-th float4
    if (i < N * 32) {
      const float4 v = *(const float4*)(x + (size_t)i * 4);
      u32 p0 = __builtin_bit_cast(u32, __builtin_amdgcn_cvt_pkrtz(v.x, v.y));
      u32 p1 = __builtin_bit_cast(u32, __builtin_amdgcn_cvt_pkrtz(v.z, v.w));
      *(uint2*)(xh + (size_t)i * 4) = uint2{p0, p1};
      u32 q = 0;
      q = __builtin_amdgcn_cvt_pk_fp8_f32(v.x, v.y, q, false);
      q = __builtin_amdgcn_cvt_pk_fp8_f32(v.z, v.w, q, true);
      xq[i] = q;
    }
  } else {                                    // ---- W -> f16 ----
    int i = (b - nba - nbx) * 256 + tid;
    if (i < 8192) {
      const float4 v = *(const float4*)(W + (size_t)i * 4);
      u32 p0 = __builtin_bit_cast(u32, __builtin_amdgcn_cvt_pkrtz(v.x, v.y));
      u32 p1 = __builtin_bit_cast(u32, __builtin_amdgcn_cvt_pkrtz(v.z, v.w));
      *(uint2*)(wh + (size_t)i * 4) = uint2{p0, p1};
    }
  }
}

// ---------------- per-bucket counting sort -> offsets[nbkt][257] + fixed-stride ssrc + nodeperm ----------------
__global__ __launch_bounds__(256) void bucket_k(const u32* __restrict__ packed,
                                                const u32* __restrict__ cnt, int N,
                                                u32* __restrict__ offsets, int* __restrict__ ssrc,
                                                u8* __restrict__ nodeperm) {
  __shared__ u32 c256[256];
  __shared__ u32 scn[256];
  __shared__ u32 cur[256];
  int b = blockIdx.x, t = threadIdx.x;
  size_t fb = (size_t)b * STRIDE;             // fixed region base
  u32 cb = cnt[b]; if (cb > (u32)STRIDE) cb = (u32)STRIDE;
  c256[t] = 0u;
  __syncthreads();
  for (u32 j = t; j < cb; j += 256) atomicAdd(&c256[packed[fb + j] >> 24], 1u);
  __syncthreads();
  u32 v = c256[t];
  scn[t] = v;
  __syncthreads();
  for (int off = 1; off < 256; off <<= 1) {
    u32 x = (t >= off) ? scn[t - off] : 0u;
    __syncthreads();
    scn[t] += x;
    __syncthreads();
  }
  u32 lbase = scn[t] - v;                     // local exclusive base of this node's segment
  int node = b * 256 + t;
  int lastT = N - 1 - b * 256; if (lastT > 255) lastT = 255;
  u32* orow = offsets + (size_t)b * 257;      // per-bucket row: no cross-bucket aliasing
  if (node < N) {
    orow[t] = (u32)(fb + lbase);
    if (t == lastT) orow[t + 1] = (u32)(fb + lbase + v);   // bucket-private terminal
  }
  cur[t] = lbase;
  __syncthreads();
  for (u32 j = t; j < cb; j += 256) {
    u32 w = packed[fb + j];
    u32 pos = atomicAdd(&cur[w >> 24], 1u);   // LDS atomic (u32)
    ssrc[fb + pos] = (int)(w & 0xFFFFFFu);
  }
  // degree-rank permutation per 32-node group (ascending degree, stable)
  {
    int g = t >> 5, l = t & 31;
    u32 mykey = c256[t] * 256u + (u32)l;
    const u32* cg = &c256[g * 32];
    u32 rank = 0;
#pragma unroll 8
    for (int l2 = 0; l2 < 32; l2++) {
      u32 k2 = cg[l2] * 256u + (u32)l2;
      rank += (k2 < mykey) ? 1u : 0u;
    }
    nodeperm[(size_t)b * 256 + g * 32 + rank] = (u8)l;
  }
}

// ---------------- fused aggregate + GEMM, 4 waves / 32 nodes per block (proven R16/R21 kernel) ----------------
#define DECV(vv, A0, A1, A2, A3) { f32x2 p;                              \
    p = __builtin_amdgcn_cvt_pk_f32_fp8((vv).x, false); A0 += p;         \
    p = __builtin_amdgcn_cvt_pk_f32_fp8((vv).x, true);  A1 += p;         \
    p = __builtin_amdgcn_cvt_pk_f32_fp8((vv).y, false); A2 += p;         \
    p = __builtin_amdgcn_cvt_pk_f32_fp8((vv).y, true);  A3 += p; }

__global__ __launch_bounds__(256) void fuse_k(const int* __restrict__ ssrc,
                                              const u32* __restrict__ offsets,
                                              const u32* __restrict__ xq,
                                              const u16* __restrict__ xh,
                                              const u16* __restrict__ wh,
                                              const float* __restrict__ bias,
                                              const u8* __restrict__ nodeperm,
                                              float* __restrict__ out, int N) {
  __shared__ u16 mlds[32][136];               // means (f16), padded stride
  int wv = threadIdx.x >> 6, lane = threadIdx.x & 63;
  int sub = lane >> 4, cl = lane & 15;
  int nbase = blockIdx.x * 32;

  // ---- phase 1: 2 rounds x 4 concurrent degree-matched nodes per wave ----
  for (int r = 0; r < 2; r++) {
    int ln = nodeperm[(size_t)nbase + r * 16 + wv * 4 + sub];
    int node = nbase + ln;
    f32x2 A0{0.f,0.f}, A1{0.f,0.f}, A2{0.f,0.f}, A3{0.f,0.f};
    u32 deg = 0;
    if (node < N) {
      size_t oi = (size_t)(node >> 8) * 257 + (node & 255);
      u32 s0 = offsets[oi], s1 = offsets[oi + 1];
      deg = s1 - s0;
      u32 j = s0;
      u32 nq = deg >> 2;
      if (nq) {
        uint4 iA = *(const uint4*)(ssrc + j);
        for (u32 q = 1; q < nq; q++) {
          uint4 iN = *(const uint4*)(ssrc + j + 4);   // prefetch next quad's indices
          uint2 v0 = *(const uint2*)(xq + ((size_t)iA.x << 5) + (cl << 1));
          uint2 v1 = *(const uint2*)(xq + ((size_t)iA.y << 5) + (cl << 1));
          uint2 v2 = *(const uint2*)(xq + ((size_t)iA.z << 5) + (cl << 1));
          uint2 v3 = *(const uint2*)(xq + ((size_t)iA.w << 5) + (cl << 1));
          DECV(v0, A0, A1, A2, A3) DECV(v1, A0, A1, A2, A3)
          DECV(v2, A0, A1, A2, A3) DECV(v3, A0, A1, A2, A3)
          iA = iN; j += 4;
        }
        {
          uint2 v0 = *(const uint2*)(xq + ((size_t)iA.x << 5) + (cl << 1));
          uint2 v1 = *(const uint2*)(xq + ((size_t)iA.y << 5) + (cl << 1));
          uint2 v2 = *(const uint2*)(xq + ((size_t)iA.z << 5) + (cl << 1));
          uint2 v3 = *(const uint2*)(xq + ((size_t)iA.w << 5) + (cl << 1));
          DECV(v0, A0, A1, A2, A3) DECV(v1, A0, A1, A2, A3)
          DECV(v2, A0, A1, A2, A3) DECV(v3, A0, A1, A2, A3)
          j += 4;
        }
      }
      for (; j < s1; j++) {
        int e = ssrc[j];
        uint2 v = *(const uint2*)(xq + ((size_t)e << 5) + (cl << 1));
        DECV(v, A0, A1, A2, A3)
      }
    }
    float inv = 1.0f / (float)(deg ? deg : 1u);
    u32 o0 = __builtin_bit_cast(u32, __builtin_amdgcn_cvt_pkrtz(A0.x * inv, A0.y * inv));
    u32 o1 = __builtin_bit_cast(u32, __builtin_amdgcn_cvt_pkrtz(A1.x * inv, A1.y * inv));
    u32 o2 = __builtin_bit_cast(u32, __builtin_amdgcn_cvt_pkrtz(A2.x * inv, A2.y * inv));
    u32 o3 = __builtin_bit_cast(u32, __builtin_amdgcn_cvt_pkrtz(A3.x * inv, A3.y * inv));
    *(uint4*)&mlds[ln][cl * 8] = uint4{o0, o1, o2, o3};   // 16 lanes cover 128 f16 feats
  }
  __syncthreads();

  // ---- phase 2: 2 strips x 2 col-halves; wave = (strip, half); f16 MFMA ----
  int la = lane & 15, lb = lane >> 4;
  int strip = wv & 1, ch = wv >> 1;
  int rbase = nbase + strip * 16;
  half8 a[8];
  const u16* ab = xh + ((size_t)(rbase + la) << 7) + lb * 8;
#pragma unroll
  for (int kb = 0; kb < 4; kb++) a[kb] = *(const half8*)(ab + kb * 32);
#pragma unroll
  for (int kb = 0; kb < 4; kb++)
    a[4 + kb] = *(const half8*)(&mlds[strip * 16 + la][kb * 32 + lb * 8]);

#pragma unroll
  for (int c = 0; c < 4; c++) {
    int ct = ch * 4 + c;
    f32x4 acc = { 0.f, 0.f, 0.f, 0.f };
    const u16* bbase = wh + ((size_t)(ct * 16 + la) << 8) + lb * 8;
#pragma unroll
    for (int kb = 0; kb < 8; kb++) {
      half8 b = *(const half8*)(bbase + kb * 32);
      acc = __builtin_amdgcn_mfma_f32_16x16x32_f16(a[kb], b, acc, 0, 0, 0);
    }
    float bc = bias[ct * 16 + la];
#pragma unroll
    for (int jj = 0; jj < 4; jj++) {
      int rr = rbase + lb * 4 + jj;
      if (rr < N) out[((size_t)rr << 7) + ct * 16 + la] = acc[jj] + bc;
    }
  }
}

extern "C" void kernel_launch(void* const* d_in, const int* in_sizes, int n_in,
                              void* d_out, int out_size, void* d_ws, size_t ws_size,
                              hipStream_t stream) {
  const float* x    = (const float*)d_in[0];
  const int*   ei   = (const int*)d_in[1];
  const float* W    = (const float*)d_in[2];
  const float* bias = (const float*)d_in[3];
  const int N = in_sizes[0] / 128;
  const int E = in_sizes[1] / 2;
  const int nbkt = (N + 255) >> 8;           // 256-node buckets (391)
  const int* src = ei;
  const int* dst = ei + E;
  float* out = (float*)d_out;

  // packed fixed-stride regions live in d_out (25.6 MB < 51.2; dead before fuse_k writes out)
  u32* packed = (u32*)d_out;                 // nbkt * STRIDE

  char* ws = (char*)d_ws;
  int* ssrc = (int*)ws;                      // nbkt * STRIDE (fixed-stride sorted srcs)
  size_t off = ((size_t)nbkt * STRIDE * 4 + 255) & ~(size_t)255;
  u32* cnt = (u32*)(ws + off);               // nbkt
  u32* offsets = cnt + nbkt;                 // nbkt * 257
  off += ((size_t)(nbkt + nbkt * 257) * 4 + 255) & ~(size_t)255;
  off = (off + 255) & ~(size_t)255;
  u16* xh = (u16*)(ws + off);                // N*128 f16 (GEMM A-half)
  off += (size_t)N * 128 * 2;
  off = (off + 255) & ~(size_t)255;
  u32* xq = (u32*)(ws + off);                // N*32 u32 (fp8 gather table)
  off += (size_t)N * 128;
  off = (off + 255) & ~(size_t)255;
  u16* wh = (u16*)(ws + off);                // 128*256 f16
  off += (size_t)128 * 256 * 2;
  off = (off + 255) & ~(size_t)255;
  u8* nodeperm = (u8*)(ws + off);            // nbkt*256 bytes

  const int nbx = (N * 32 + 255) / 256;
  const int nba = (E + 8191) / 8192;
  hipMemsetAsync(cnt, 0, (size_t)nbkt * 4, stream);
  part_k<<<nba + nbx + 32, 256, 0, stream>>>(src, dst, E, cnt, packed, nbkt,
                                             x, xh, xq, W, wh, N, nba, nbx);
  bucket_k<<<nbkt, 256, 0, stream>>>(packed, cnt, N, offsets, ssrc, nodeperm);
  fuse_k<<<(N + 31) / 32, 256, 0, stream>>>(ssrc, offsets, xq, xh, wh, bias, nodeperm, out, N);
}